// Round 6
// baseline (204.300 us; speedup 1.0000x reference)
//
#include <hip/hip_runtime.h>

#define ALPHA 0.1f
#define NUM_CLASSES 10

typedef __attribute__((ext_vector_type(8))) short bf16x8;
typedef __attribute__((ext_vector_type(4))) float f32x4;

// ---------------------------------------------------------------------------
// ws layout (bytes):
//   ctpk  @ 0     : uint4[16ct][4f][64lane]  center A-frags, Dekker split
//                   f: 0=ch k0-31, 1=ch k32-63, 2=cl k0-31, 3=cl k32-63
//   c2    @ 65536 : float[256]
//   loss  @ 66560 : float[1]
//   counts@ 66564 : uint[100]
//   done  @ 66964 : uint[1]
// prep zeroes loss/counts/done (stream order makes it visible to dist).
// ---------------------------------------------------------------------------

__device__ __forceinline__ unsigned pack2(float a, float b) {
    // bf16(a) lo16 | bf16(b) hi16 (truncation -> exact Dekker hi split)
    return (__float_as_uint(b) & 0xFFFF0000u) | (__float_as_uint(a) >> 16);
}
__device__ __forceinline__ float truncbf(float a) {
    return __uint_as_float(__float_as_uint(a) & 0xFFFF0000u);
}

// ---------------------------------------------------------------------------

__global__ __launch_bounds__(256) void prep_kernel(
    const float* __restrict__ centers,
    unsigned int* __restrict__ ctpk,
    float* __restrict__ c2,
    float* __restrict__ loss_acc,
    unsigned int* __restrict__ counts,
    unsigned int* __restrict__ done)
{
    const int k = threadIdx.x;          // center id 0..255
    const int ct = k >> 4, r = k & 15;

    float cv[64];
    float s = 0.f;
    const float4* crow = (const float4*)(centers + k * 64);
#pragma unroll
    for (int j4 = 0; j4 < 16; ++j4) {
        float4 v = crow[j4];
        cv[j4 * 4 + 0] = v.x; cv[j4 * 4 + 1] = v.y;
        cv[j4 * 4 + 2] = v.z; cv[j4 * 4 + 3] = v.w;
        s += v.x * v.x + v.y * v.y + v.z * v.z + v.w * v.w;
    }
    c2[k] = s;

    uint4* out4 = (uint4*)ctpk;
#pragma unroll
    for (int f = 0; f < 4; ++f) {
#pragma unroll
        for (int q = 0; q < 4; ++q) {
            const int cbase = (f & 1) * 32 + q * 8;   // k-col of j=0
            unsigned wv[4];
#pragma unroll
            for (int j2 = 0; j2 < 4; ++j2) {
                float a = cv[cbase + j2 * 2], b = cv[cbase + j2 * 2 + 1];
                if (f >= 2) { a = a - truncbf(a); b = b - truncbf(b); }  // cl
                wv[j2] = pack2(a, b);
            }
            out4[(ct * 4 + f) * 64 + q * 16 + r] =
                make_uint4(wv[0], wv[1], wv[2], wv[3]);
        }
    }
    if (k < NUM_CLASSES * NUM_CLASSES) counts[k] = 0u;
    if (k == 100) loss_acc[0] = 0.f;
    if (k == 101) done[0] = 0u;
}

// ---------------------------------------------------------------------------
// dist kernel: 256 threads = 4 INDEPENDENT waves; wave w owns 64 points
// (blockIdx*256 + w*64 ..) x all 256 centers. Centers = M of the MFMA,
// points = N: C/D row = center (q*4+reg), col = point (r). swe/swd/argmin
// finish inside the wave (shfl over q) -> zero barriers, zero LDS in the
// hot path. Center frags stream from L2-resident ctpk with next-ct prefetch.
// Points go in two 32-point halves to keep live VGPRs ~110 (<=128 cap from
// __launch_bounds__(256,4) -> 16 waves/CU; grid = N/256 = 1024 = exactly
// 4 blocks/CU resident, no tail).
// Finalize fused: last block (device-scope done counter) computes out[].
// ---------------------------------------------------------------------------

__global__ __launch_bounds__(256, 4) void dist_kernel(
    const float* __restrict__ x,
    const int*   __restrict__ y,
    const uint4* __restrict__ ctpk4,
    const float* __restrict__ c2g,
    float* __restrict__ loss_acc,
    unsigned int* __restrict__ counts,
    unsigned int* __restrict__ done,
    float* __restrict__ out,
    int N)
{
    const int tid  = threadIdx.x;
    const int w    = tid >> 6;
    const int lane = tid & 63;
    const int q    = lane >> 4;
    const int r    = lane & 15;
    const int base = blockIdx.x * 256 + w * 64;   // this wave's 64 points

    float loss_local = 0.f;

#pragma unroll 1
    for (int h = 0; h < 2; ++h) {
        // ---- convert 32 points (2 subtiles) to split-bf16 B-frags ----
        bf16x8 bh0[2], bh1[2], bl0[2], bl1[2];
        float x2p[2];
#pragma unroll
        for (int s = 0; s < 2; ++s) {
            const int row = base + h * 32 + s * 16 + r;
            const float4* X = (const float4*)(x + (size_t)row * 64);
            float4 v0 = X[q * 2], v1 = X[q * 2 + 1];       // k = q*8..
            float4 v2 = X[8 + q * 2], v3 = X[9 + q * 2];   // k = 32+q*8..

            float p = v0.x * v0.x;
            p = fmaf(v0.y, v0.y, p); p = fmaf(v0.z, v0.z, p); p = fmaf(v0.w, v0.w, p);
            p = fmaf(v1.x, v1.x, p); p = fmaf(v1.y, v1.y, p); p = fmaf(v1.z, v1.z, p); p = fmaf(v1.w, v1.w, p);
            p = fmaf(v2.x, v2.x, p); p = fmaf(v2.y, v2.y, p); p = fmaf(v2.z, v2.z, p); p = fmaf(v2.w, v2.w, p);
            p = fmaf(v3.x, v3.x, p); p = fmaf(v3.y, v3.y, p); p = fmaf(v3.z, v3.z, p); p = fmaf(v3.w, v3.w, p);
            p += __shfl_xor(p, 16);
            p += __shfl_xor(p, 32);   // all lanes: ||x_{s*16+r}||^2 (matches epilogue col r)
            x2p[s] = p;

            union { bf16x8 v; unsigned u[4]; } h0, h1, l0, l1;
            h0.u[0] = pack2(v0.x, v0.y); h0.u[1] = pack2(v0.z, v0.w);
            h0.u[2] = pack2(v1.x, v1.y); h0.u[3] = pack2(v1.z, v1.w);
            h1.u[0] = pack2(v2.x, v2.y); h1.u[1] = pack2(v2.z, v2.w);
            h1.u[2] = pack2(v3.x, v3.y); h1.u[3] = pack2(v3.z, v3.w);
            l0.u[0] = pack2(v0.x - truncbf(v0.x), v0.y - truncbf(v0.y));
            l0.u[1] = pack2(v0.z - truncbf(v0.z), v0.w - truncbf(v0.w));
            l0.u[2] = pack2(v1.x - truncbf(v1.x), v1.y - truncbf(v1.y));
            l0.u[3] = pack2(v1.z - truncbf(v1.z), v1.w - truncbf(v1.w));
            l1.u[0] = pack2(v2.x - truncbf(v2.x), v2.y - truncbf(v2.y));
            l1.u[1] = pack2(v2.z - truncbf(v2.z), v2.w - truncbf(v2.w));
            l1.u[2] = pack2(v3.x - truncbf(v3.x), v3.y - truncbf(v3.y));
            l1.u[3] = pack2(v3.z - truncbf(v3.z), v3.w - truncbf(v3.w));
            bh0[s] = h0.v; bh1[s] = h1.v; bl0[s] = l0.v; bl1[s] = l1.v;
        }

        float swe[2] = {0.f, 0.f}, swd[2] = {0.f, 0.f};
        unsigned best[2] = {0xFFFFFFFFu, 0xFFFFFFFFu};

        // ---- stream 16 center groups; prefetch ct+1 during ct's compute ----
        uint4 na0 = ctpk4[0 * 64 + lane], na1 = ctpk4[1 * 64 + lane];
        uint4 na2 = ctpk4[2 * 64 + lane], na3 = ctpk4[3 * 64 + lane];
        float4 nc2 = *(const float4*)(c2g + q * 4);

#pragma unroll 1
        for (int ct = 0; ct < 16; ++ct) {
            union { uint4 u; bf16x8 v; } af0, af1, af2, af3;
            af0.u = na0; af1.u = na1; af2.u = na2; af3.u = na3;
            const float c2a0 = nc2.x, c2a1 = nc2.y, c2a2 = nc2.z, c2a3 = nc2.w;

            if (ct < 15) {
                const int nb = (ct + 1) * 4 * 64;
                na0 = ctpk4[nb + 0 * 64 + lane];
                na1 = ctpk4[nb + 1 * 64 + lane];
                na2 = ctpk4[nb + 2 * 64 + lane];
                na3 = ctpk4[nb + 3 * 64 + lane];
                nc2 = *(const float4*)(c2g + (ct + 1) * 16 + q * 4);
            }

            f32x4 acc[2];
#pragma unroll
            for (int s = 0; s < 2; ++s) {
                f32x4 a = (f32x4){0.f, 0.f, 0.f, 0.f};
                a = __builtin_amdgcn_mfma_f32_16x16x32_bf16(af0.v, bh0[s], a, 0, 0, 0); // ch.xh
                a = __builtin_amdgcn_mfma_f32_16x16x32_bf16(af1.v, bh1[s], a, 0, 0, 0);
                a = __builtin_amdgcn_mfma_f32_16x16x32_bf16(af2.v, bh0[s], a, 0, 0, 0); // cl.xh
                a = __builtin_amdgcn_mfma_f32_16x16x32_bf16(af3.v, bh1[s], a, 0, 0, 0);
                a = __builtin_amdgcn_mfma_f32_16x16x32_bf16(af0.v, bl0[s], a, 0, 0, 0); // ch.xl
                a = __builtin_amdgcn_mfma_f32_16x16x32_bf16(af1.v, bl1[s], a, 0, 0, 0);
                acc[s] = a;
            }

#pragma unroll
            for (int s = 0; s < 2; ++s) {
                const float x2v = x2p[s];
                const float c2a[4] = {c2a0, c2a1, c2a2, c2a3};
#pragma unroll
                for (int reg = 0; reg < 4; ++reg) {
                    float d = fmaf(-2.f, acc[s][reg], x2v + c2a[reg]);
                    d = fmaxf(d, 0.f);
                    const unsigned kid = (unsigned)(ct * 16 + q * 4 + reg);
                    unsigned u = (__float_as_uint(d) & 0xFFFFFF00u) | kid;
                    best[s] = min(best[s], u);
                    float wg = exp2f(-ALPHA * __log2f(1.f + d));
                    swe[s] += wg;
                    swd[s] = fmaf(wg, d, swd[s]);
                }
            }
        }

        // ---- per-point finish (reduce over the 4 q-lanes of col r) ----
#pragma unroll
        for (int s = 0; s < 2; ++s) {
            float SWE = swe[s], SWD = swd[s];
            unsigned B = best[s];
            SWE += __shfl_xor(SWE, 16); SWE += __shfl_xor(SWE, 32);
            SWD += __shfl_xor(SWD, 16); SWD += __shfl_xor(SWD, 32);
            B = min(B, (unsigned)__shfl_xor((int)B, 16));
            B = min(B, (unsigned)__shfl_xor((int)B, 32));
            if (q == 0) {
                loss_local += SWD / SWE;
                const unsigned bk = B & 0xFFu;
                if (bk < NUM_CLASSES) {
                    const int lbl = y[base + h * 32 + s * 16 + r];
                    atomicAdd(&counts[bk * NUM_CLASSES + lbl], 1u);
                }
            }
        }
    }

    // ---- loss: wave-local reduce, one atomic per wave ----
    float v = loss_local;
#pragma unroll
    for (int o = 32; o > 0; o >>= 1) v += __shfl_down(v, o);
    if (lane == 0) atomicAdd(loss_acc, v);

    // ---- fused finalize: last block to finish does the greedy assignment ----
    __syncthreads();
    if (tid == 0) {
        __threadfence();
        if (atomicAdd(done, 1u) == gridDim.x - 1) {
            __threadfence();
            float c[NUM_CLASSES][NUM_CLASSES];
            for (int i = 0; i < NUM_CLASSES; ++i)
                for (int j = 0; j < NUM_CLASSES; ++j)
                    c[i][j] = (float)atomicAdd(&counts[i * NUM_CLASSES + j], 0u);
            const float L = atomicAdd(loss_acc, 0.f);

            bool used[NUM_CLASSES];
            for (int i = 0; i < NUM_CLASSES; ++i) used[i] = false;
            float correct = 0.f;
            for (int i = 0; i < NUM_CLASSES; ++i) {
                float rowsum = 0.f;
                for (int j = 0; j < NUM_CLASSES; ++j) rowsum += c[i][j];
                const bool has_points = rowsum > 0.f;

                int label = 0;
                float mx = c[i][0];
                for (int j = 1; j < NUM_CLASSES; ++j)
                    if (c[i][j] > mx) { mx = c[i][j]; label = j; }

                if (used[label]) {
                    float mm = used[0] ? 0.f : c[i][0];
                    int l2 = 0;
                    for (int j = 1; j < NUM_CLASSES; ++j) {
                        float vv = used[j] ? 0.f : c[i][j];
                        if (vv > mm) { mm = vv; l2 = j; }
                    }
                    label = l2;
                }
                if (has_points) {
                    correct += c[i][label];
                    used[label] = true;
                }
            }
            out[0] = L;
            out[1] = correct / (float)N;
        }
    }
}

// ---------------------------------------------------------------------------

extern "C" void kernel_launch(void* const* d_in, const int* in_sizes, int n_in,
                              void* d_out, int out_size, void* d_ws, size_t ws_size,
                              hipStream_t stream)
{
    const float* x       = (const float*)d_in[0];
    const int*   y       = (const int*)d_in[1];
    const float* centers = (const float*)d_in[2];
    float* out = (float*)d_out;

    const int N = in_sizes[0] / 64;   // D = 64

    unsigned int* ctpk   = (unsigned int*)d_ws;                    // 65536 B
    float* c2            = (float*)((char*)d_ws + 65536);          // 1024 B
    float* loss          = (float*)((char*)d_ws + 66560);          // 4 B
    unsigned int* counts = (unsigned int*)((char*)d_ws + 66564);   // 400 B
    unsigned int* done   = (unsigned int*)((char*)d_ws + 66964);   // 4 B

    prep_kernel<<<1, 256, 0, stream>>>(centers, ctpk, c2, loss, counts, done);

    const int grid = N / 256;   // one 256-point tile per block; 4 blocks/CU
    dist_kernel<<<grid, 256, 0, stream>>>(x, y, (const uint4*)ctpk, c2,
                                          loss, counts, done, out, N);
}